// Round 8
// baseline (237.001 us; speedup 1.0000x reference)
//
#include <hip/hip_runtime.h>
#include <math.h>

// PCEN: x[B=64, C=128, T=4000] fp32.
// smooth[0]=x[0]; smooth[t]=(1-s)*smooth[t-1]+s*x[t], s=0.025
// out = sqrt(x/(smooth+1e-6)^0.98 + 2) - sqrt(2)
//
// R8 = R7 resubmitted verbatim (R7 bench died on container infrastructure,
// not the kernel). Theory under test: FILLBUFFER-SHAPED EXECUTION.
// R0-R6 falsified VALU-issue, MLP, barrier, store-policy and
// shallow-pipeline theories; dur pinned at 79-85us, HBM at ~2.4 TB/s (31%)
// while fillBufferAligned sustains 6.6 TB/s on the same device with 768
// long-lived waves each streaming ~680 KB contiguously in a tight loop.
// The untested axis is STREAM SHAPE: all prior versions used 4096-16384
// one-shot waves touching <=32 KB each. Here: 2048 waves (2/SIMD), wave w
// owns channels [4w,4w+4) = 64 KB contiguous in + 64 KB out, processed as
// 8 half-channel stages with register ping-pong (va/vb): issue next stage's
// 8 loads -> sched_barrier(0) -> compute current stage. Waves issue memory
// ops continuously for their entire life. Math is the R3/R6-verified
// formulation (literal scan coefficients, (1-s)^256 compose, per-lane
// (1-s)^(4*lane) via one v_exp_f32), bit-identical.

constexpr int   TLEN = 4000;
constexpr int   NF4  = 1000;   // float4 chunks per channel
constexpr int   NTH  = 256;
constexpr int   HALF = 8;      // scan columns per stage (half channel)
constexpr int   CPW  = 4;      // channels per wave
constexpr float S_C  = 0.025f;
constexpr float A_1  = 1.0f - S_C;

typedef float f4_t __attribute__((ext_vector_type(4)));   // native vec for nt-store

constexpr float fpow(float b, int n) {
    float r = 1.0f;
    for (int i = 0; i < n; ++i) r *= b;
    return r;
}
constexpr float A_2  = fpow(A_1, 2);
constexpr float A_3  = fpow(A_1, 3);
constexpr float A256 = fpow(A_1, 256);   // one segment = 64 lanes * 4 elems

// 4*log2(1-s): per-lane exclusive coefficient is exp2(lane * L2A4)
constexpr float L2A4 = -0.14610359f;

constexpr float ALPHA = 0.98f;
constexpr float EPS_C = 1e-6f;
constexpr float SQRT2 = 1.41421356237309515f;

__device__ __forceinline__ float pcen_elem(float x, float sm) {
    float t = sm + EPS_C;
    float p = __builtin_amdgcn_exp2f(-ALPHA * __builtin_amdgcn_logf(t)); // t^-alpha
    float y = fmaf(x, p, 2.0f);
    return __builtin_amdgcn_sqrtf(y) - SQRT2;
}

__device__ __forceinline__ void load_half(f4_t (&v)[HALF], const f4_t* __restrict__ x4,
                                          int lane, int h /*compile-time*/) {
#pragma unroll
    for (int j = 0; j < HALF; ++j) {
        const int f4 = lane + 64 * (h * HALF + j);
        v[j] = (f4 < NF4) ? x4[f4] : (f4_t){0.f, 0.f, 0.f, 0.f};
    }
}

// Compute one half-channel stage: scan 8 columns, epilogue, store.
// h must be a compile-time constant at each call.
__device__ __forceinline__ void compute_half(const f4_t (&v)[HALF], f4_t* __restrict__ o4,
                                             int lane, float Al, float& e,
                                             int h, bool store_ok) {
    constexpr float CD[6] = { fpow(A_1, 4),  fpow(A_1, 8),  fpow(A_1, 16),
                              fpow(A_1, 32), fpow(A_1, 64), fpow(A_1, 128) };
    // per-chunk offset B (coefficient uniformly A_1^4)
    float B[HALF];
#pragma unroll
    for (int j = 0; j < HALF; ++j) {
        f4_t  r  = v[j];
        float b0 = (h == 0 && j == 0 && lane == 0) ? r.x : S_C * r.x;  // smooth[0]=x[0]
        B[j] = fmaf(A_3, b0, S_C * fmaf(A_2, r.y, fmaf(A_1, r.z, r.w)));
    }
    // inclusive wave scan: 6 shuffle steps x 8 independent columns
#pragma unroll
    for (int s = 0; s < 6; ++s) {
        const int   d  = 1 << s;
        const float cc = CD[s];
        float Bp[HALF];
#pragma unroll
        for (int j = 0; j < HALF; ++j) Bp[j] = __shfl_up(B[j], d);
        const bool ok = (lane >= d);
#pragma unroll
        for (int j = 0; j < HALF; ++j) B[j] = fmaf(cc, ok ? Bp[j] : 0.0f, B[j]);
    }
    // epilogue per column: exclusive shuffle, replay, pcen, nt-store
#pragma unroll
    for (int j = 0; j < HALF; ++j) {
        const int k  = h * HALF + j;
        float Tk = __shfl(B[j], 63);             // segment total
        float Bi = __shfl_up(B[j], 1);
        if (lane == 0) Bi = 0.0f;
        float sm = fmaf(Al, e, Bi);              // smoothed value entering chunk

        f4_t  r  = v[j];
        float b0 = (h == 0 && j == 0 && lane == 0) ? r.x : S_C * r.x;
        float s0 = fmaf(A_1, sm, b0);
        float s1 = fmaf(A_1, s0, S_C * r.y);
        float s2 = fmaf(A_1, s1, S_C * r.z);
        float s3 = fmaf(A_1, s2, S_C * r.w);

        f4_t o;
        o.x = pcen_elem(r.x, s0);
        o.y = pcen_elem(r.y, s1);
        o.z = pcen_elem(r.z, s2);
        o.w = pcen_elem(r.w, s3);

        const int f4 = lane + 64 * k;
        if (store_ok && f4 < NF4) __builtin_nontemporal_store(o, &o4[f4]);

        e = fmaf(A256, e, Tk);                   // advance to next segment
    }
}

__global__ __launch_bounds__(NTH) void pcen_kernel(const float* __restrict__ x,
                                                   float* __restrict__ out,
                                                   int nch) {
    const int lane = threadIdx.x & 63;
    const int wid  = blockIdx.x * (NTH / 64) + (threadIdx.x >> 6);
    const int cb   = wid * CPW;                  // 4 contiguous channels per wave
    if (cb >= nch) return;

    const bool h1 = (cb + 1 < nch), h2 = (cb + 2 < nch), h3 = (cb + 3 < nch);
    const size_t b0 = (size_t)cb * TLEN;
    const size_t b1 = (size_t)(h1 ? cb + 1 : cb) * TLEN;
    const size_t b2 = (size_t)(h2 ? cb + 2 : cb) * TLEN;
    const size_t b3 = (size_t)(h3 ? cb + 3 : cb) * TLEN;

    const f4_t* __restrict__ x0 = (const f4_t*)(x + b0);
    const f4_t* __restrict__ x1 = (const f4_t*)(x + b1);
    const f4_t* __restrict__ x2 = (const f4_t*)(x + b2);
    const f4_t* __restrict__ x3 = (const f4_t*)(x + b3);
    f4_t* __restrict__ o0 = (f4_t*)(out + b0);
    f4_t* __restrict__ o1 = (f4_t*)(out + b1);
    f4_t* __restrict__ o2 = (f4_t*)(out + b2);
    f4_t* __restrict__ o3 = (f4_t*)(out + b3);

    const float Al = __builtin_amdgcn_exp2f((float)lane * L2A4);

    f4_t  va[HALF], vb[HALF];
    float e = 0.0f;

    // ---- 8-stage steady-state pipeline: issue next loads, then compute ----
    load_half(va, x0, lane, 0);
    __builtin_amdgcn_sched_barrier(0);

    load_half(vb, x0, lane, 1);                   // (c0,h1) in flight
    __builtin_amdgcn_sched_barrier(0);
    compute_half(va, o0, lane, Al, e, 0, true);   // c0 h0

    load_half(va, x1, lane, 0);                   // (c1,h0) in flight
    __builtin_amdgcn_sched_barrier(0);
    compute_half(vb, o0, lane, Al, e, 1, true);   // c0 h1

    load_half(vb, x1, lane, 1);                   // (c1,h1) in flight
    __builtin_amdgcn_sched_barrier(0);
    e = 0.0f;
    compute_half(va, o1, lane, Al, e, 0, h1);     // c1 h0

    load_half(va, x2, lane, 0);                   // (c2,h0) in flight
    __builtin_amdgcn_sched_barrier(0);
    compute_half(vb, o1, lane, Al, e, 1, h1);     // c1 h1

    load_half(vb, x2, lane, 1);                   // (c2,h1) in flight
    __builtin_amdgcn_sched_barrier(0);
    e = 0.0f;
    compute_half(va, o2, lane, Al, e, 0, h2);     // c2 h0

    load_half(va, x3, lane, 0);                   // (c3,h0) in flight
    __builtin_amdgcn_sched_barrier(0);
    compute_half(vb, o2, lane, Al, e, 1, h2);     // c2 h1

    load_half(vb, x3, lane, 1);                   // (c3,h1) in flight
    __builtin_amdgcn_sched_barrier(0);
    e = 0.0f;
    compute_half(va, o3, lane, Al, e, 0, h3);     // c3 h0

    compute_half(vb, o3, lane, Al, e, 1, h3);     // c3 h1
}

extern "C" void kernel_launch(void* const* d_in, const int* in_sizes, int n_in,
                              void* d_out, int out_size, void* d_ws, size_t ws_size,
                              hipStream_t stream) {
    const float* x   = (const float*)d_in[0];
    float*       out = (float*)d_out;
    const int nch    = in_sizes[0] / TLEN;               // 8192 channels
    const int wpb    = NTH / 64;                         // 4 waves per block
    const int nw     = (nch + CPW - 1) / CPW;            // 2048 waves
    const int grid   = (nw + wpb - 1) / wpb;             // 512 blocks
    pcen_kernel<<<grid, NTH, 0, stream>>>(x, out, nch);
}

// Round 9
// 228.152 us; speedup vs baseline: 1.0388x; 1.0388x over previous
//
#include <hip/hip_runtime.h>
#include <math.h>

// PCEN: x[B=64, C=128, T=4000] fp32.
// smooth[0]=x[0]; smooth[t]=(1-s)*smooth[t-1]+s*x[t], s=0.025
// out = sqrt(x/(smooth+1e-6)^0.98 + 2) - sqrt(2)
//
// R9: ASYNC global_load_lds STAGING (the one untouched mechanism).
// R0-R8: every VGPR-return-load structure (any VALU count, MLP, wave count,
// barrier/pipeline/stream shape) pins at ~80us / 2.4 TB/s; Little's law at
// 600ns latency -> ~45 outstanding 128B reads per CU, i.e. a VGPR-return
// read-queue cap. global_load_lds is the deeper async DMA path (no VGPR
// writeback; guide Common-mistake #1: compiler never auto-emits it).
// Structure: one wave per channel (8192 waves), half-channel (8 KB) staged
// to LDS; half1's 8 async loads are issued BEFORE half0's compute (counted
// vmcnt(8) wait; 8 epilogue stores issue after all 16 loads so the count
// excludes them). LDS 32 KB/block -> 5 blocks/CU = 20 waves/CU;
// ~160 KB async reads in flight per CU >> ~16 KB needed for peak BW.
// Math is the R3/R6-verified formulation, bit-identical.

constexpr int   TLEN = 4000;
constexpr int   NF4  = 1000;   // float4 chunks per channel
constexpr int   NTH  = 256;
constexpr int   HALF = 8;      // columns per half-channel
constexpr float S_C  = 0.025f;
constexpr float A_1  = 1.0f - S_C;

typedef float f4_t __attribute__((ext_vector_type(4)));

constexpr float fpow(float b, int n) {
    float r = 1.0f;
    for (int i = 0; i < n; ++i) r *= b;
    return r;
}
constexpr float A_2  = fpow(A_1, 2);
constexpr float A_3  = fpow(A_1, 3);
constexpr float A256 = fpow(A_1, 256);   // one segment = 64 lanes * 4 elems

// 4*log2(1-s): per-lane exclusive coefficient is exp2(lane * L2A4)
constexpr float L2A4 = -0.14610359f;

constexpr float ALPHA = 0.98f;
constexpr float EPS_C = 1e-6f;
constexpr float SQRT2 = 1.41421356237309515f;

__device__ __forceinline__ float pcen_elem(float x, float sm) {
    float t = sm + EPS_C;
    float p = __builtin_amdgcn_exp2f(-ALPHA * __builtin_amdgcn_logf(t)); // t^-alpha
    float y = fmaf(x, p, 2.0f);
    return __builtin_amdgcn_sqrtf(y) - SQRT2;
}

// One half-channel: B-offsets, 6-step shuffle scan over 8 columns, epilogue.
// H is the half index (compile-time); e is the running segment-entering value.
template <int H>
__device__ __forceinline__ void compute_half(const f4_t (&r)[HALF], f4_t* __restrict__ o4,
                                             int lane, float Al, float& e) {
    constexpr float CD[6] = { fpow(A_1, 4),  fpow(A_1, 8),  fpow(A_1, 16),
                              fpow(A_1, 32), fpow(A_1, 64), fpow(A_1, 128) };
    // per-chunk offset B (coefficient uniformly A_1^4)
    float B[HALF];
#pragma unroll
    for (int j = 0; j < HALF; ++j) {
        float b0 = (H == 0 && j == 0 && lane == 0) ? r[j].x : S_C * r[j].x;  // smooth[0]=x[0]
        B[j] = fmaf(A_3, b0, S_C * fmaf(A_2, r[j].y, fmaf(A_1, r[j].z, r[j].w)));
    }
    // inclusive wave scan: 6 shuffle steps x 8 independent columns
#pragma unroll
    for (int s = 0; s < 6; ++s) {
        const int   d  = 1 << s;
        const float cc = CD[s];
        float Bp[HALF];
#pragma unroll
        for (int j = 0; j < HALF; ++j) Bp[j] = __shfl_up(B[j], d);
        const bool ok = (lane >= d);
#pragma unroll
        for (int j = 0; j < HALF; ++j) B[j] = fmaf(cc, ok ? Bp[j] : 0.0f, B[j]);
    }
    // epilogue per column: exclusive shuffle, replay, pcen, store
#pragma unroll
    for (int j = 0; j < HALF; ++j) {
        const int k  = H * HALF + j;
        float Tk = __shfl(B[j], 63);             // segment total
        float Bi = __shfl_up(B[j], 1);
        if (lane == 0) Bi = 0.0f;
        float sm = fmaf(Al, e, Bi);              // smoothed value entering chunk

        float b0 = (H == 0 && j == 0 && lane == 0) ? r[j].x : S_C * r[j].x;
        float s0 = fmaf(A_1, sm, b0);
        float s1 = fmaf(A_1, s0, S_C * r[j].y);
        float s2 = fmaf(A_1, s1, S_C * r[j].z);
        float s3 = fmaf(A_1, s2, S_C * r[j].w);

        f4_t o;
        o.x = pcen_elem(r[j].x, s0);
        o.y = pcen_elem(r[j].y, s1);
        o.z = pcen_elem(r[j].z, s2);
        o.w = pcen_elem(r[j].w, s3);

        const int f4 = lane + 64 * k;
        if (f4 < NF4) o4[f4] = o;

        e = fmaf(A256, e, Tk);                   // advance to next segment
    }
}

__global__ __launch_bounds__(NTH) void pcen_kernel(const float* __restrict__ x,
                                                   float* __restrict__ out,
                                                   int nch) {
    __shared__ f4_t lds[NTH / 64][HALF][64];     // 4 waves x 8 KB = 32 KB/block
    const int lane = threadIdx.x & 63;
    const int wv   = threadIdx.x >> 6;
    const int ch   = blockIdx.x * (NTH / 64) + wv;
    if (ch >= nch) return;                       // no barriers anywhere: safe

    const f4_t* __restrict__ x4 = (const f4_t*)(x + (size_t)ch * TLEN);
    f4_t*       __restrict__ o4 = (f4_t*)(out + (size_t)ch * TLEN);

    // ---- issue half0's 8 async loads (cols 0..7; all indices < 512 < NF4) ----
#pragma unroll
    for (int j = 0; j < HALF; ++j) {
        const f4_t* src = x4 + (64 * j + lane);
        __builtin_amdgcn_global_load_lds(
            (const __attribute__((address_space(1))) void*)src,
            (__attribute__((address_space(3))) void*)&lds[wv][j][0], 16, 0, 0);
    }

    const float Al = __builtin_amdgcn_exp2f((float)lane * L2A4);
    float e = 0.0f;

    // ---- half 0: wait loads, pull to regs, then issue half1 loads ----
    asm volatile("s_waitcnt vmcnt(0)" ::: "memory");
    __builtin_amdgcn_sched_barrier(0);
    f4_t r0[HALF];
#pragma unroll
    for (int j = 0; j < HALF; ++j) r0[j] = lds[wv][j][lane];
    asm volatile("s_waitcnt lgkmcnt(0)" ::: "memory");   // regs valid: LDS reusable
    __builtin_amdgcn_sched_barrier(0);

    // issue half1's 8 async loads into the SAME buffer (cols 8..15, clamped)
#pragma unroll
    for (int j = 0; j < HALF; ++j) {
        int f4i = 64 * (HALF + j) + lane;
        int idx = (f4i < NF4) ? f4i : (NF4 - 1);         // clamp; masked at use
        const f4_t* src = x4 + idx;
        __builtin_amdgcn_global_load_lds(
            (const __attribute__((address_space(1))) void*)src,
            (__attribute__((address_space(3))) void*)&lds[wv][j][0], 16, 0, 0);
    }
    __builtin_amdgcn_sched_barrier(0);

    compute_half<0>(r0, o4, lane, Al, e);        // runs under half1's loads

    // ---- half 1: loads 8..15 done when completed>=16; 8 stores issued after
    //      all loads, so vmcnt(8) tolerates exactly the outstanding stores ----
    asm volatile("s_waitcnt vmcnt(8)" ::: "memory");
    __builtin_amdgcn_sched_barrier(0);
    f4_t r1[HALF];
#pragma unroll
    for (int j = 0; j < HALF; ++j) {
        r1[j] = lds[wv][j][lane];
        const int f4i = 64 * (HALF + j) + lane;
        if (f4i >= NF4) r1[j] = (f4_t){0.f, 0.f, 0.f, 0.f};   // tail = padding
    }
    compute_half<1>(r1, o4, lane, Al, e);
}

extern "C" void kernel_launch(void* const* d_in, const int* in_sizes, int n_in,
                              void* d_out, int out_size, void* d_ws, size_t ws_size,
                              hipStream_t stream) {
    const float* x   = (const float*)d_in[0];
    float*       out = (float*)d_out;
    const int nch    = in_sizes[0] / TLEN;               // 8192 channels
    const int wpb    = NTH / 64;                         // 4 waves (channels) per block
    const int grid   = (nch + wpb - 1) / wpb;            // 2048 blocks
    pcen_kernel<<<grid, NTH, 0, stream>>>(x, out, nch);
}